// Round 11
// baseline (34.328 us; speedup 1.0000x reference)
//
#include <hip/hip_runtime.h>

#define PAGE     64
#define LSEQ     8192
#define BROWS    32
#define MAXPAGES 8192
#define MP64     (MAXPAGES * PAGE)   // 524288 slots per row

// element offsets (int32 elements) into flat d_out, reference return order:
// token_valid, page_indices, page_valid, segment_ids, token2page
#define OFF_TV   0
#define OFF_PI   (BROWS * LSEQ)                        // 262144
#define OFF_PV   (OFF_PI + BROWS * MP64)               // 17039360
#define OFF_SI   (OFF_PV + BROWS * MP64)               // 33816576
#define OFF_T2P  (OFF_SI + BROWS * MAXPAGES)           // 34078720

// Tend <= 2L+62: each non-qp flush pad (64-c) <= that segment's length - 1
// (flush requires sl > 64-c), so sum(pads) <= L-1; plus one qp flush <= 63.
#define TSAFE    16448                 // layout-dependent PI/PV prefix (int4-aligned)
#define TSAFE4   (TSAFE / 4)           // 4112 = 8 * 514
#define GRP_SUB  514                   // prefix int4-groups per fore sub-block
#define SIPREF4  65                    // SI int4 groups in fore: elements [0,260)
#define CAPSEG   2048                  // LDS segment-table capacity

#define NFORE    (BROWS * 8)           // 256 fore blocks, 8 per row
#define NFILL    1792
#define NBLK     (NFORE + NFILL)       // 2048
#define R4       (MP64 / 4)            // 131072 (pow2)
#define SIR4     (MAXPAGES / 4)        // 2048 (pow2)
#define PIPV4    (BROWS * R4)          // 4194304 int4 per region
#define CHNK     2341                  // ceil(PIPV4 / NFILL): int4 per fill block
#define SI4      (BROWS * SIR4)        // 65536 int4
#define CHNKSI   37                    // ceil(SI4 / NFILL)

// ws spill only if nseg > CAPSEG (unreachable for bench data; benign identical-
// value races among the 8 sub-blocks of a row if it ever triggers)
#define WROW       (8 + 2 * (LSEQ + 2))
#define WS_NEEDED  ((size_t)BROWS * WROW * sizeof(int))

typedef int v4i __attribute__((ext_vector_type(4)));
__device__ __forceinline__ void st4(int* p, v4i v) { *(v4i*)p = v; }
__device__ __forceinline__ v4i mk4(int a, int b, int c, int d) {
    v4i r; r.x = a; r.y = b; r.z = c; r.w = d; return r;
}

__global__ __launch_bounds__(256) void SegmentPager_fused(
        const int* __restrict__ ids,
        const int* __restrict__ mask,
        const int* __restrict__ qpos,
        int* __restrict__ ws, int wsOk,
        int* __restrict__ out) {
    const int tid = threadIdx.x;

    // ===== fill blocks: background regions, BLOCK-CONTIGUOUS chunks (DRAM page
    // locality: each block sweeps one ~37 KB window sequentially, vs grid-stride's
    // 7168 interleaved streams).
    if (blockIdx.x >= NFORE) {
        const unsigned b = blockIdx.x - NFORE;
        const v4i M1 = mk4(-1, -1, -1, -1);
        const v4i Z0 = mk4(0, 0, 0, 0);
        const unsigned lo = b * CHNK;
        const unsigned hiE = (lo + CHNK < PIPV4) ? lo + CHNK : PIPV4;
        int* piB = out + OFF_PI;
        for (unsigned i = lo + tid; i < hiE; i += 256)      // ~9.1 iters
            if ((i & (R4 - 1)) >= TSAFE4) st4(piB + 4u * i, M1);
        int* pvB = out + OFF_PV;
        for (unsigned i = lo + tid; i < hiE; i += 256)
            if ((i & (R4 - 1)) >= TSAFE4) st4(pvB + 4u * i, Z0);
        int* siB = out + OFF_SI;
        unsigned iS = b * CHNKSI + tid;
        if (tid < CHNKSI && iS < SI4 && (iS & (SIR4 - 1)) >= SIPREF4)
            st4(siB + 4u * iS, M1);
        return;
    }

    // ===== fore blocks: redundant per-row setup + 1/8 of dependent region
    __shared__ unsigned int sBits[LSEQ / 32];   // 256 words
    __shared__ int sS[CAPSEG + 1];
    __shared__ int sT[CAPSEG + 1];
    __shared__ int sMeta[4];                    // [0]=nseg [1]=any_valid [2]=Tend

    const int row = blockIdx.x >> 3;
    const int sub = blockIdx.x & 7;
    int qp = qpos[row];
    qp = qp < 0 ? 0 : (qp > LSEQ ? LSEQ : qp);

    const int* idr = ids  + (size_t)row * LSEQ;
    const int* mkr = mask + (size_t)row * LSEQ;
    int* wrow = ws ? (ws + (size_t)row * WROW) : nullptr;

    sBits[tid] = 0u;
    if (tid < 4) sMeta[tid] = 0;
    __syncthreads();

    // --- Phase 1: start-bits (nl at i -> start i+1; pos 0; pos qp) + any_valid
    int myany = 0;
    for (int g = tid; g < LSEQ / 4; g += 256) {            // 8 iters
        int4 x = *(const int4*)(idr + g * 4);
        int4 m = *(const int4*)(mkr + g * 4);
        int b = g * 4;
        if (x.x == 13 && b + 1 < LSEQ) atomicOr(&sBits[(b + 1) >> 5], 1u << ((b + 1) & 31));
        if (x.y == 13 && b + 2 < LSEQ) atomicOr(&sBits[(b + 2) >> 5], 1u << ((b + 2) & 31));
        if (x.z == 13 && b + 3 < LSEQ) atomicOr(&sBits[(b + 3) >> 5], 1u << ((b + 3) & 31));
        if (x.w == 13 && b + 4 < LSEQ) atomicOr(&sBits[(b + 4) >> 5], 1u << ((b + 4) & 31));
        myany |= m.x | m.y | m.z | m.w;
    }
    if (tid == 0) {
        atomicOr(&sBits[0], 1u);
        if (qp < LSEQ) atomicOr(&sBits[qp >> 5], 1u << (qp & 31));
    }
    if (myany) sMeta[1] = 1;                               // benign all-write-1 race
    __syncthreads();

    // --- Phase 2 (wave 0): ordered compaction of set bits
    if (tid < 64) {
        unsigned int w0 = sBits[4 * tid + 0];
        unsigned int w1 = sBits[4 * tid + 1];
        unsigned int w2 = sBits[4 * tid + 2];
        unsigned int w3 = sBits[4 * tid + 3];
        int cnt = __popc(w0) + __popc(w1) + __popc(w2) + __popc(w3);
        int off = cnt;
        for (int d = 1; d < 64; d <<= 1) {                 // inclusive scan
            int n = __shfl_up(off, d);
            if (tid >= d) off += n;
        }
        int total = __shfl(off, 63);
        off -= cnt;                                        // exclusive
        if (tid == 0) sMeta[0] = total;
        const bool spill = (total > CAPSEG) && wsOk;
        int* dst = spill ? (wrow + 8) : sS;
        const int cap = spill ? (LSEQ + 2) : (CAPSEG + 1);
        unsigned int wd[4] = {w0, w1, w2, w3};
        int base = tid * 128;
#pragma unroll
        for (int w = 0; w < 4; ++w) {
            unsigned int word = wd[w];
            while (word) {
                int b = __ffs(word) - 1;
                word &= word - 1;
                int o = off++;
                if (o < cap) dst[o] = base + 32 * w + b;
            }
        }
    }
    __syncthreads();

    int count = sMeta[0];
    const bool spill = (count > CAPSEG) && wsOk;
    if (!spill && count > CAPSEG) count = CAPSEG;          // unreachable safety clamp
    const int* S  = spill ? (const int*)(wrow + 8) : (const int*)sS;
    int*       Td = spill ? (wrow + 8 + (LSEQ + 2)) : sT;

    // --- Phase 3 (serial, ~nseg iters): fill position at each segment start
    if (tid == 0) {
        int T = 0;
        for (int s = 0; s < count; ++s) {
            int p  = S[s];
            int pn = (s + 1 < count) ? S[s + 1] : LSEQ;
            int sl = pn - p;
            int c  = T & (PAGE - 1);
            if (c > 0 && (p == qp || sl > PAGE - c)) T += PAGE - c;  // flush pad
            Td[s] = T;
            T += sl;
        }
        sMeta[2] = T;
    }
    __syncthreads();

    const int nseg = count;
    const int av   = sMeta[1];
    const int Tend = av ? sMeta[2] : 0;        // degenerate row: all background
    const int* Tt = Td;

    // --- PI + PV over this sub-block's share of [0, TSAFE)
    int* pi = out + OFF_PI + (size_t)row * MP64;
    int* pv = out + OFF_PV + (size_t)row * MP64;
    for (int g = sub * GRP_SUB + tid; g < (sub + 1) * GRP_SUB; g += 256) {  // ~2 iters
        int T = g * 4;
        v4i vi = mk4(-1, -1, -1, -1);
        v4i vv = mk4(0, 0, 0, 0);
        if (T < Tend) {
            int r[4] = {-1, -1, -1, -1}, v[4] = {0, 0, 0, 0};
#pragma unroll
            for (int k = 0; k < 4; ++k) {
                int Tk = T + k;
                if (Tk < Tend) {
                    int lo = 0, hi = nseg - 1;
                    while (lo < hi) {                      // largest s: Tt[s] <= Tk
                        int mid = (lo + hi + 1) >> 1;
                        if (Tt[mid] <= Tk) lo = mid; else hi = mid - 1;
                    }
                    int pos  = S[lo] + (Tk - Tt[lo]);
                    int send = (lo + 1 < nseg) ? S[lo + 1] : LSEQ;
                    if (pos < send) { r[k] = pos; v[k] = (mkr[pos] != 0); }  // else pad
                }
            }
            vi = mk4(r[0], r[1], r[2], r[3]);
            vv = mk4(v[0], v[1], v[2], v[3]);
        }
        st4(pi + T, vi);
        st4(pv + T, vv);
    }

    // --- SI pages [0,260): slot 0 of a live page is always a token; dead -> -1
    if (sub == 0 && tid < SIPREF4) {
        int sid[4];
#pragma unroll
        for (int k = 0; k < 4; ++k) {
            int T0 = (tid * 4 + k) * PAGE;
            int s = -1;
            if (T0 < Tend) {
                int lo = 0, hi = nseg - 1;
                while (lo < hi) {
                    int mid = (lo + hi + 1) >> 1;
                    if (Tt[mid] <= T0) lo = mid; else hi = mid - 1;
                }
                s = lo;
            }
            sid[k] = s;
        }
        st4(out + OFF_SI + (size_t)row * MAXPAGES + tid * 4,
            mk4(sid[0], sid[1], sid[2], sid[3]));
    }

    // --- TV + T2P: this sub-block's 1024 tokens (1 int4 group per thread)
    {
        int g = sub * 256 + tid;                           // group in [0, 2048)
        int4 m = *(const int4*)(mkr + g * 4);
        st4(out + OFF_TV + (size_t)row * LSEQ + g * 4,
            mk4(m.x != 0, m.y != 0, m.z != 0, m.w != 0));
        v4i t2 = mk4(-1, -1, -1, -1);
        if (av) {
            int t2a[4];
#pragma unroll
            for (int k = 0; k < 4; ++k) {
                int i = g * 4 + k;
                int lo = 0, hi = nseg - 1;
                while (lo < hi) {                          // largest s: S[s] <= i
                    int mid = (lo + hi + 1) >> 1;
                    if (S[mid] <= i) lo = mid; else hi = mid - 1;
                }
                t2a[k] = (Tt[lo] + (i - S[lo])) >> 6;
            }
            t2 = mk4(t2a[0], t2a[1], t2a[2], t2a[3]);
        }
        st4(out + OFF_T2P + (size_t)row * LSEQ + g * 4, t2);
    }
}

extern "C" void kernel_launch(void* const* d_in, const int* in_sizes, int n_in,
                              void* d_out, int out_size, void* d_ws, size_t ws_size,
                              hipStream_t stream) {
    const int* ids  = (const int*)d_in[0];
    const int* mask = (const int*)d_in[1];
    const int* qpos = (const int*)d_in[2];
    int* out = (int*)d_out;
    int* ws  = (int*)d_ws;
    int wsOk = (ws != nullptr && ws_size >= WS_NEEDED) ? 1 : 0;

    SegmentPager_fused<<<NBLK, 256, 0, stream>>>(ids, mask, qpos, ws, wsOk, out);
}

// Round 12
// 33.578 us; speedup vs baseline: 1.0223x; 1.0223x over previous
//
#include <hip/hip_runtime.h>

#define PAGE     64
#define LSEQ     8192
#define BROWS    32
#define MAXPAGES 8192
#define MP64     (MAXPAGES * PAGE)   // 524288 slots per row

// element offsets (int32 elements) into flat d_out, reference return order:
// token_valid, page_indices, page_valid, segment_ids, token2page
#define OFF_TV   0
#define OFF_PI   (BROWS * LSEQ)                        // 262144
#define OFF_PV   (OFF_PI + BROWS * MP64)               // 17039360
#define OFF_SI   (OFF_PV + BROWS * MP64)               // 33816576
#define OFF_T2P  (OFF_SI + BROWS * MAXPAGES)           // 34078720

// Tend <= 2L+62: each non-qp flush pad (64-c) <= that segment's length - 1
// (flush requires sl > 64-c), so sum(pads) <= L-1; plus one qp flush <= 63.
#define TSAFE    16448                 // layout-dependent PI/PV prefix (int4-aligned)
#define TSAFE4   (TSAFE / 4)           // 4112 = 8 * 514
#define GRP_SUB  514                   // prefix int4-groups per fore sub-block
#define SIPREF4  65                    // SI int4 groups in fore: elements [0,260)
#define CAPSEG   2048                  // LDS segment-table capacity

#define NFORE    (BROWS * 8)           // 256 fore blocks, 8 per row
#define NFILL    256                   // ONE fill block per CU (memset-like geometry)
#define NBLK     (NFORE + NFILL)       // 512
#define R4       (MP64 / 4)            // 131072 (pow2)
#define SIR4     (MAXPAGES / 4)        // 2048 (pow2)
#define PIPV4    (BROWS * R4)          // 4194304 int4 per region
#define FCH      (PIPV4 / NFILL)       // 16384 int4 per fill block (exact)
#define SI4      (BROWS * SIR4)        // 65536 int4
#define FCHSI    (SI4 / NFILL)         // 256 int4 per fill block (exact)

// ws spill only if nseg > CAPSEG (unreachable for bench data; benign identical-
// value races among the 8 sub-blocks of a row if it ever triggers)
#define WROW       (8 + 2 * (LSEQ + 2))
#define WS_NEEDED  ((size_t)BROWS * WROW * sizeof(int))

typedef int v4i __attribute__((ext_vector_type(4)));
__device__ __forceinline__ void st4(int* p, v4i v) { *(v4i*)p = v; }
__device__ __forceinline__ v4i mk4(int a, int b, int c, int d) {
    v4i r; r.x = a; r.y = b; r.z = c; r.w = d; return r;
}

__global__ __launch_bounds__(256) void SegmentPager_fused(
        const int* __restrict__ ids,
        const int* __restrict__ mask,
        const int* __restrict__ qpos,
        int* __restrict__ ws, int wsOk,
        int* __restrict__ out) {
    const int tid = threadIdx.x;

    // ===== fill blocks: one per CU, each sweeping long contiguous windows
    // (mimics fillBufferAligned's proven 6.6 TB/s low-stream-count geometry).
    if (blockIdx.x >= NFORE) {
        const unsigned b = blockIdx.x - NFORE;
        const v4i M1 = mk4(-1, -1, -1, -1);
        const v4i Z0 = mk4(0, 0, 0, 0);
        const unsigned lo = b * FCH;
        int* piB = out + OFF_PI;
        for (unsigned i = lo + tid; i < lo + FCH; i += 256)   // 64 iters, 256 KB
            if ((i & (R4 - 1)) >= TSAFE4) st4(piB + 4u * i, M1);
        int* pvB = out + OFF_PV;
        for (unsigned i = lo + tid; i < lo + FCH; i += 256)   // 64 iters, 256 KB
            if ((i & (R4 - 1)) >= TSAFE4) st4(pvB + 4u * i, Z0);
        int* siB = out + OFF_SI;
        unsigned iS = b * FCHSI + tid;                        // 1 store
        if ((iS & (SIR4 - 1)) >= SIPREF4) st4(siB + 4u * iS, M1);
        return;
    }

    // ===== fore blocks: redundant per-row setup + 1/8 of dependent region
    __shared__ unsigned int sBits[LSEQ / 32];   // 256 words
    __shared__ int sS[CAPSEG + 1];
    __shared__ int sT[CAPSEG + 1];
    __shared__ int sMeta[4];                    // [0]=nseg [1]=any_valid [2]=Tend

    const int row = blockIdx.x >> 3;
    const int sub = blockIdx.x & 7;
    int qp = qpos[row];
    qp = qp < 0 ? 0 : (qp > LSEQ ? LSEQ : qp);

    const int* idr = ids  + (size_t)row * LSEQ;
    const int* mkr = mask + (size_t)row * LSEQ;
    int* wrow = ws ? (ws + (size_t)row * WROW) : nullptr;

    sBits[tid] = 0u;
    if (tid < 4) sMeta[tid] = 0;
    __syncthreads();

    // --- Phase 1: start-bits (nl at i -> start i+1; pos 0; pos qp) + any_valid
    int myany = 0;
    for (int g = tid; g < LSEQ / 4; g += 256) {            // 8 iters
        int4 x = *(const int4*)(idr + g * 4);
        int4 m = *(const int4*)(mkr + g * 4);
        int b = g * 4;
        if (x.x == 13 && b + 1 < LSEQ) atomicOr(&sBits[(b + 1) >> 5], 1u << ((b + 1) & 31));
        if (x.y == 13 && b + 2 < LSEQ) atomicOr(&sBits[(b + 2) >> 5], 1u << ((b + 2) & 31));
        if (x.z == 13 && b + 3 < LSEQ) atomicOr(&sBits[(b + 3) >> 5], 1u << ((b + 3) & 31));
        if (x.w == 13 && b + 4 < LSEQ) atomicOr(&sBits[(b + 4) >> 5], 1u << ((b + 4) & 31));
        myany |= m.x | m.y | m.z | m.w;
    }
    if (tid == 0) {
        atomicOr(&sBits[0], 1u);
        if (qp < LSEQ) atomicOr(&sBits[qp >> 5], 1u << (qp & 31));
    }
    if (myany) sMeta[1] = 1;                               // benign all-write-1 race
    __syncthreads();

    // --- Phase 2 (wave 0): ordered compaction of set bits
    if (tid < 64) {
        unsigned int w0 = sBits[4 * tid + 0];
        unsigned int w1 = sBits[4 * tid + 1];
        unsigned int w2 = sBits[4 * tid + 2];
        unsigned int w3 = sBits[4 * tid + 3];
        int cnt = __popc(w0) + __popc(w1) + __popc(w2) + __popc(w3);
        int off = cnt;
        for (int d = 1; d < 64; d <<= 1) {                 // inclusive scan
            int n = __shfl_up(off, d);
            if (tid >= d) off += n;
        }
        int total = __shfl(off, 63);
        off -= cnt;                                        // exclusive
        if (tid == 0) sMeta[0] = total;
        const bool spill = (total > CAPSEG) && wsOk;
        int* dst = spill ? (wrow + 8) : sS;
        const int cap = spill ? (LSEQ + 2) : (CAPSEG + 1);
        unsigned int wd[4] = {w0, w1, w2, w3};
        int base = tid * 128;
#pragma unroll
        for (int w = 0; w < 4; ++w) {
            unsigned int word = wd[w];
            while (word) {
                int b = __ffs(word) - 1;
                word &= word - 1;
                int o = off++;
                if (o < cap) dst[o] = base + 32 * w + b;
            }
        }
    }
    __syncthreads();

    int count = sMeta[0];
    const bool spill = (count > CAPSEG) && wsOk;
    if (!spill && count > CAPSEG) count = CAPSEG;          // unreachable safety clamp
    const int* S  = spill ? (const int*)(wrow + 8) : (const int*)sS;
    int*       Td = spill ? (wrow + 8 + (LSEQ + 2)) : sT;

    // --- Phase 3 (serial, ~nseg iters): fill position at each segment start
    if (tid == 0) {
        int T = 0;
        for (int s = 0; s < count; ++s) {
            int p  = S[s];
            int pn = (s + 1 < count) ? S[s + 1] : LSEQ;
            int sl = pn - p;
            int c  = T & (PAGE - 1);
            if (c > 0 && (p == qp || sl > PAGE - c)) T += PAGE - c;  // flush pad
            Td[s] = T;
            T += sl;
        }
        sMeta[2] = T;
    }
    __syncthreads();

    const int nseg = count;
    const int av   = sMeta[1];
    const int Tend = av ? sMeta[2] : 0;        // degenerate row: all background
    const int* Tt = Td;

    // --- PI + PV over this sub-block's share of [0, TSAFE)
    int* pi = out + OFF_PI + (size_t)row * MP64;
    int* pv = out + OFF_PV + (size_t)row * MP64;
    for (int g = sub * GRP_SUB + tid; g < (sub + 1) * GRP_SUB; g += 256) {  // ~2 iters
        int T = g * 4;
        v4i vi = mk4(-1, -1, -1, -1);
        v4i vv = mk4(0, 0, 0, 0);
        if (T < Tend) {
            int r[4] = {-1, -1, -1, -1}, v[4] = {0, 0, 0, 0};
#pragma unroll
            for (int k = 0; k < 4; ++k) {
                int Tk = T + k;
                if (Tk < Tend) {
                    int lo = 0, hi = nseg - 1;
                    while (lo < hi) {                      // largest s: Tt[s] <= Tk
                        int mid = (lo + hi + 1) >> 1;
                        if (Tt[mid] <= Tk) lo = mid; else hi = mid - 1;
                    }
                    int pos  = S[lo] + (Tk - Tt[lo]);
                    int send = (lo + 1 < nseg) ? S[lo + 1] : LSEQ;
                    if (pos < send) { r[k] = pos; v[k] = (mkr[pos] != 0); }  // else pad
                }
            }
            vi = mk4(r[0], r[1], r[2], r[3]);
            vv = mk4(v[0], v[1], v[2], v[3]);
        }
        st4(pi + T, vi);
        st4(pv + T, vv);
    }

    // --- SI pages [0,260): slot 0 of a live page is always a token; dead -> -1
    if (sub == 0 && tid < SIPREF4) {
        int sid[4];
#pragma unroll
        for (int k = 0; k < 4; ++k) {
            int T0 = (tid * 4 + k) * PAGE;
            int s = -1;
            if (T0 < Tend) {
                int lo = 0, hi = nseg - 1;
                while (lo < hi) {
                    int mid = (lo + hi + 1) >> 1;
                    if (Tt[mid] <= T0) lo = mid; else hi = mid - 1;
                }
                s = lo;
            }
            sid[k] = s;
        }
        st4(out + OFF_SI + (size_t)row * MAXPAGES + tid * 4,
            mk4(sid[0], sid[1], sid[2], sid[3]));
    }

    // --- TV + T2P: this sub-block's 1024 tokens (1 int4 group per thread)
    {
        int g = sub * 256 + tid;                           // group in [0, 2048)
        int4 m = *(const int4*)(mkr + g * 4);
        st4(out + OFF_TV + (size_t)row * LSEQ + g * 4,
            mk4(m.x != 0, m.y != 0, m.z != 0, m.w != 0));
        v4i t2 = mk4(-1, -1, -1, -1);
        if (av) {
            int t2a[4];
#pragma unroll
            for (int k = 0; k < 4; ++k) {
                int i = g * 4 + k;
                int lo = 0, hi = nseg - 1;
                while (lo < hi) {                          // largest s: S[s] <= i
                    int mid = (lo + hi + 1) >> 1;
                    if (S[mid] <= i) lo = mid; else hi = mid - 1;
                }
                t2a[k] = (Tt[lo] + (i - S[lo])) >> 6;
            }
            t2 = mk4(t2a[0], t2a[1], t2a[2], t2a[3]);
        }
        st4(out + OFF_T2P + (size_t)row * LSEQ + g * 4, t2);
    }
}

extern "C" void kernel_launch(void* const* d_in, const int* in_sizes, int n_in,
                              void* d_out, int out_size, void* d_ws, size_t ws_size,
                              hipStream_t stream) {
    const int* ids  = (const int*)d_in[0];
    const int* mask = (const int*)d_in[1];
    const int* qpos = (const int*)d_in[2];
    int* out = (int*)d_out;
    int* ws  = (int*)d_ws;
    int wsOk = (ws != nullptr && ws_size >= WS_NEEDED) ? 1 : 0;

    SegmentPager_fused<<<NBLK, 256, 0, stream>>>(ids, mask, qpos, ws, wsOk, out);
}